// Round 1
// baseline (380.154 us; speedup 1.0000x reference)
//
#include <hip/hip_runtime.h>
#include <hip/hip_bf16.h>

// Capsule dynamic routing, fused recompute design.
// Shapes: x[B=64][J=2048][I=16], W[N=32][J=2048][D=16][I=16], out v[B=64][N=32][D=16]
//
// Math identity: b_k[b,n,j] = (sum_{i<k} v_i[b,n,:]) . u_hat[b,n,j,:]  (u_hat const
// across iterations), so we keep only vsum[B,N,D] (128 KB) and recompute u_hat
// per pass (3 passes). Pass 1 with vsum=0 -> logits 0 -> softmax uniform = 1/32,
// exactly the reference's first iteration.
//
// routing_pass: block = 512 threads = 16 half-waves. Half-wave h owns batches
// b0=g*32+2h, b1=b0+1 (grid.y=2 covers B=64). lane&31 = n, so softmax over N is a
// 5-step __shfl_xor butterfly inside a 32-lane half (no LDS, no barrier).
// W[:,j,:,:] (32 KB) staged in LDS with row stride 258 floats: float2 reads across
// the 32 n-lanes land on distinct bank-pairs (only the free 2-way alias); stride
// 256 would be a 16-way conflict. s-partials accumulate in regs over JC=8 j's,
// then spill to sp[chunk][b][n][d] (32 MB of d_ws) -- no atomics, deterministic.
// reduce_squash: folds the 256 chunk-partials, applies squash, updates vsum
// (passes 0,1) or writes d_out (pass 2).

#define J_DIM 2048
#define JC 8            // j's per block chunk
#define NCHUNK (J_DIM / JC)  // 256
#define WROW 258        // LDS row stride (floats) for W: even (8B align) and 258/2=129 odd -> conflict-free b64

__global__ __launch_bounds__(512, 1)
void routing_pass(const float* __restrict__ x, const float* __restrict__ W,
                  const float* __restrict__ vsum, float* __restrict__ sp) {
    __shared__ float lw[32 * WROW];   // ~33 KB

    const int t = threadIdx.x;          // 0..511
    const int n = t & 31;               // capsule index (lane within half-wave)
    const int h = t >> 5;               // half-wave id 0..15
    const int g = blockIdx.y;           // batch group 0..1
    const int b0 = g * 32 + 2 * h;
    const int b1 = b0 + 1;
    const int chunk = blockIdx.x;       // 0..255
    const int jbase = chunk * JC;

    // W staging mapping: thread copies 16 consecutive floats of one n-row
    const int sn = t >> 4;              // 0..31  (n row)
    const int sk = t & 15;              // 0..15  (16-float piece -> d = sk)

    float acc0[16], acc1[16];
#pragma unroll
    for (int d = 0; d < 16; ++d) { acc0[d] = 0.f; acc1[d] = 0.f; }

    for (int js = 0; js < JC; ++js) {
        const int j = jbase + js;
        __syncthreads();  // protect previous iteration's lw reads
        {
            // global: W[sn, j, sk, 0..15] -> contiguous 64B per thread, 1KB per n-group
            const float4* src = (const float4*)(W + (size_t)sn * 524288 + (size_t)j * 256 + sk * 16);
            float4 q0 = src[0], q1 = src[1], q2 = src[2], q3 = src[3];
            float2* dst = (float2*)&lw[sn * WROW + sk * 16];
            dst[0] = make_float2(q0.x, q0.y); dst[1] = make_float2(q0.z, q0.w);
            dst[2] = make_float2(q1.x, q1.y); dst[3] = make_float2(q1.z, q1.w);
            dst[4] = make_float2(q2.x, q2.y); dst[5] = make_float2(q2.z, q2.w);
            dst[6] = make_float2(q3.x, q3.y); dst[7] = make_float2(q3.z, q3.w);
        }
        __syncthreads();

        // x rows for our two batches (same addr across the 32-lane half -> broadcast)
        float x0[16], x1[16];
        {
            const float4* x0p = (const float4*)(x + (size_t)b0 * 32768 + (size_t)j * 16);
            const float4* x1p = (const float4*)(x + (size_t)b1 * 32768 + (size_t)j * 16);
#pragma unroll
            for (int q = 0; q < 4; ++q) {
                float4 a = x0p[q];
                x0[4*q] = a.x; x0[4*q+1] = a.y; x0[4*q+2] = a.z; x0[4*q+3] = a.w;
                float4 c = x1p[q];
                x1[4*q] = c.x; x1[4*q+1] = c.y; x1[4*q+2] = c.z; x1[4*q+3] = c.w;
            }
        }

        // u[b, n, d] = sum_i W[n,j,d,i] * x[b,j,i]
        float u0[16], u1[16];
#pragma unroll
        for (int d = 0; d < 16; ++d) {
            float s0 = 0.f, s1 = 0.f;
            const float2* wr = (const float2*)&lw[n * WROW + d * 16];
#pragma unroll
            for (int i2 = 0; i2 < 8; ++i2) {
                float2 w2 = wr[i2];
                s0 = fmaf(w2.x, x0[2*i2], s0);
                s0 = fmaf(w2.y, x0[2*i2+1], s0);
                s1 = fmaf(w2.x, x1[2*i2], s1);
                s1 = fmaf(w2.y, x1[2*i2+1], s1);
            }
            u0[d] = s0; u1[d] = s1;
        }

        // logits = vsum[b,n,:] . u  (vsum L2-hot, same addr across half-wave)
        const float* vs0 = vsum + ((size_t)b0 * 32 + n) * 16;
        const float* vs1 = vsum + ((size_t)b1 * 32 + n) * 16;
        float l0 = 0.f, l1 = 0.f;
#pragma unroll
        for (int d = 0; d < 16; ++d) {
            l0 = fmaf(vs0[d], u0[d], l0);
            l1 = fmaf(vs1[d], u1[d], l1);
        }

        // softmax over n: butterfly within the 32-lane half (masks <= 16)
        float m0 = l0, m1 = l1;
#pragma unroll
        for (int mk = 16; mk >= 1; mk >>= 1) {
            m0 = fmaxf(m0, __shfl_xor(m0, mk));
            m1 = fmaxf(m1, __shfl_xor(m1, mk));
        }
        float e0 = __expf(l0 - m0), e1 = __expf(l1 - m1);
        float s0 = e0, s1 = e1;
#pragma unroll
        for (int mk = 16; mk >= 1; mk >>= 1) {
            s0 += __shfl_xor(s0, mk);
            s1 += __shfl_xor(s1, mk);
        }
        float p0 = e0 * __builtin_amdgcn_rcpf(s0);
        float p1 = e1 * __builtin_amdgcn_rcpf(s1);

#pragma unroll
        for (int d = 0; d < 16; ++d) {
            acc0[d] = fmaf(p0, u0[d], acc0[d]);
            acc1[d] = fmaf(p1, u1[d], acc1[d]);
        }
    }

    // partial store: sp[chunk][b][n][d], contiguous 64B per thread, coalesced across n
    float* o0 = sp + (((size_t)chunk * 64 + b0) * 32 + n) * 16;
    float* o1 = sp + (((size_t)chunk * 64 + b1) * 32 + n) * 16;
#pragma unroll
    for (int q = 0; q < 4; ++q) {
        ((float4*)o0)[q] = make_float4(acc0[4*q], acc0[4*q+1], acc0[4*q+2], acc0[4*q+3]);
        ((float4*)o1)[q] = make_float4(acc1[4*q], acc1[4*q+1], acc1[4*q+2], acc1[4*q+3]);
    }
}

// One wave per (b,n): fold 256 chunk-partials, squash, update vsum / write out.
__global__ __launch_bounds__(64)
void reduce_squash(const float* __restrict__ sp, float* __restrict__ vsum,
                   float* __restrict__ out, int is_last) {
    const int bn = blockIdx.x;       // 0..2047 -> (b = bn>>5, n = bn&31)
    const int l = threadIdx.x;       // 0..63
    const int d = l & 15;
    const int cg = l >> 4;           // 4 chunk groups

    float a = 0.f;
    const float* base = sp + (size_t)bn * 16 + d;
#pragma unroll 8
    for (int m = 0; m < 64; ++m) {
        int c = cg * 64 + m;
        a += base[(size_t)c * 32768];
    }
    // fold the 4 chunk groups (lanes l, l^16, l^32, l^48 share d)
    a += __shfl_xor(a, 16);
    a += __shfl_xor(a, 32);

    // squash: s2 = sum_d a^2 + eps
    float tt = a * a;
    tt += __shfl_xor(tt, 1);
    tt += __shfl_xor(tt, 2);
    tt += __shfl_xor(tt, 4);
    tt += __shfl_xor(tt, 8);
    float s2 = tt + 1e-7f;
    float scale = sqrtf(s2) / (1.0f + s2);
    float v = scale * a;

    if (l < 16) {
        if (is_last) out[bn * 16 + d] = v;
        else         vsum[bn * 16 + d] += v;   // single writer per element
    }
}

extern "C" void kernel_launch(void* const* d_in, const int* in_sizes, int n_in,
                              void* d_out, int out_size, void* d_ws, size_t ws_size,
                              hipStream_t stream) {
    const float* x = (const float*)d_in[0];   // [64,2048,16]
    const float* W = (const float*)d_in[1];   // [32,2048,16,16]
    float* out = (float*)d_out;               // [64,32,16]

    float* sp   = (float*)d_ws;               // [256][64][32][16] = 32 MB partials
    float* vsum = sp + (size_t)NCHUNK * 64 * 32 * 16;  // [64][32][16] = 128 KB

    hipMemsetAsync(vsum, 0, 64 * 32 * 16 * sizeof(float), stream);

    dim3 grid(NCHUNK, 2), blk(512);
    for (int pass = 0; pass < 3; ++pass) {
        routing_pass<<<grid, blk, 0, stream>>>(x, W, vsum, sp);
        reduce_squash<<<2048, 64, 0, stream>>>(sp, vsum, out, pass == 2);
    }
}